// Round 10
// baseline (55.716 us; speedup 1.0000x reference)
//
#include <hip/hip_runtime.h>

// out[b,s,:] = W[:, text[b,s]] + bias + pe[s,:]
// text: int32 [B,S]; W: f32 [D, VOCAB]; bias: f32 [D]; pe: f32 [MAX_LEN, D]
//
// Round 10 (= round 9 + compile fix): r7 gather (best, 40.2us) + two levers:
//  (1) parallel 3-kernel binning (hist/scan/scatter) -> shrink serial prefix;
//  (2) nontemporal W loads / out stores (touch-once streams) -> keep L2 for pe.
// Fix: __builtin_nontemporal_load needs a native clang vector type, not HIP's
// float4 class. Use ext_vector_type(4).

#define VOCAB  32000
#define DMODEL 1024
#define S_LEN  2048
#define B_N    4
#define NTOK   (B_N * S_LEN)     // 8192
#define VT     64                // vocab entries per tile
#define DT     64                // d rows per tile
#define NBIN   (VOCAB / VT)      // 500
#define NDT    (DMODEL / DT)     // 16
#define NBLK   (NBIN * NDT)      // 8000
#define LSTRIDE (VT + 1)         // 65: column reads 2-way only (free)

typedef float f4 __attribute__((ext_vector_type(4)));

// ---- pass 1a: parallel histogram (global atomics over 500 bins) ----
__global__ __launch_bounds__(256) void hist_k(const int* __restrict__ text,
                                              int* __restrict__ hist) {
    const int i = blockIdx.x * 256 + threadIdx.x;
    if (i < NTOK) atomicAdd(&hist[text[i] >> 6], 1);
}

// ---- pass 1b: scan 500 bins; tile_off = exclusive starts; hist <- cursor ----
__global__ __launch_bounds__(512) void scan_k(int* __restrict__ hist,
                                              int* __restrict__ tile_off) {
    __shared__ int scn[512];
    const int t = threadIdx.x;
    const int cnt = (t < NBIN) ? hist[t] : 0;
    scn[t] = cnt;
    __syncthreads();
    for (int off = 1; off < 512; off <<= 1) {
        int x = (t >= off) ? scn[t - off] : 0;
        __syncthreads();
        scn[t] += x;
        __syncthreads();
    }
    if (t < NBIN) {
        const int start = scn[t] - cnt;      // exclusive
        tile_off[t] = start;
        hist[t] = start;                     // becomes scatter cursor
    }
    if (t == 0) tile_off[NBIN] = NTOK;
}

// ---- pass 1c: parallel scatter (order within bin irrelevant) ----
__global__ __launch_bounds__(256) void scatter_k(const int* __restrict__ text,
                                                 int* __restrict__ cursor,
                                                 int2* __restrict__ sorted) {
    const int i = blockIdx.x * 256 + threadIdx.x;
    if (i < NTOK) {
        const int tok = text[i];
        const int slot = atomicAdd(&cursor[tok >> 6], 1);
        sorted[slot] = make_int2(tok, i);
    }
}

// ---- pass 2: coalesced nt W sweep, LDS-staged scatter-free gather ----
__global__ __launch_bounds__(256, 8) void gather_k(const int2* __restrict__ sorted,
                                                   const int* __restrict__ tile_off,
                                                   const float* __restrict__ W,
                                                   const float* __restrict__ bias,
                                                   const float* __restrict__ pe,
                                                   float* __restrict__ out) {
    __shared__ float lds[DT * LSTRIDE];      // 16.6 KB -> 8 blocks/CU

    const int bid = blockIdx.x;
    const int vt = bid >> 4;                 // 0..499
    const int dt = bid & (NDT - 1);          // 0..15 (bid%8 ~ dt%8 -> XCD affinity)
    const int v0 = vt * VT;
    const int d0 = dt * DT;
    const int t  = threadIdx.x;

    // stage W[d0:d0+64][v0:v0+64] into LDS; nt: W is touch-once streaming
    {
        const int c4 = t & 15;               // float4 column 0..15
        const int r0 = t >> 4;               // row 0..15
        #pragma unroll
        for (int i = 0; i < 4; ++i) {
            const int row = r0 + i * 16;
            const f4 w4 = __builtin_nontemporal_load(
                reinterpret_cast<const f4*>(
                    W + (size_t)(d0 + row) * VOCAB + v0 + c4 * 4));
            float* lp = lds + row * LSTRIDE + c4 * 4;
            lp[0] = w4.x; lp[1] = w4.y; lp[2] = w4.z; lp[3] = w4.w;
        }
    }
    __syncthreads();

    const int a0 = tile_off[vt];
    const int a1 = tile_off[vt + 1];
    const int lane = t & 63;
    const int wv   = t >> 6;                 // 4 tokens in parallel
    const float bv = bias[d0 + lane];

    for (int i = a0 + wv; i < a1; i += 4) {
        const int2 p = sorted[i];            // wave-uniform broadcast
        const int tokl = p.x - v0;
        const int bs   = p.y;
        const int s    = bs & (S_LEN - 1);
        const float wval = lds[lane * LSTRIDE + tokl];   // (lane+tokl)%32: 2-way
        const float pv = pe[(size_t)s * DMODEL + d0 + lane];
        __builtin_nontemporal_store(wval + bv + pv,
                                    out + (size_t)bs * DMODEL + d0 + lane);
    }
}

// ---- fallback (ws too small): direct gather ----
__global__ __launch_bounds__(256) void embed_pe_direct(const int* __restrict__ text,
                                                       const float* __restrict__ W,
                                                       const float* __restrict__ bias,
                                                       const float* __restrict__ pe,
                                                       float* __restrict__ out) {
    const int bs = blockIdx.x;
    const int s  = bs & (S_LEN - 1);
    const int tok = text[bs];
    const int d = threadIdx.x << 2;
    const float4 b4 = *reinterpret_cast<const float4*>(bias + d);
    const float4 p4 = *reinterpret_cast<const float4*>(pe + (size_t)s * DMODEL + d);
    const float* wcol = W + (size_t)d * VOCAB + tok;
    float4 o;
    o.x = wcol[0]                 + b4.x + p4.x;
    o.y = wcol[(size_t)VOCAB]     + b4.y + p4.y;
    o.z = wcol[(size_t)2 * VOCAB] + b4.z + p4.z;
    o.w = wcol[(size_t)3 * VOCAB] + b4.w + p4.w;
    *reinterpret_cast<float4*>(out + (size_t)bs * DMODEL + d) = o;
}

extern "C" void kernel_launch(void* const* d_in, const int* in_sizes, int n_in,
                              void* d_out, int out_size, void* d_ws, size_t ws_size,
                              hipStream_t stream) {
    const int*   text = (const int*)d_in[0];
    const float* W    = (const float*)d_in[1];
    const float* bias = (const float*)d_in[2];
    const float* pe   = (const float*)d_in[3];
    float*       out  = (float*)d_out;

    const size_t sorted_bytes = (size_t)NTOK * sizeof(int2);   // 64 KB
    const size_t off_bytes    = (NBIN + 1) * sizeof(int);
    const size_t hist_bytes   = NBIN * sizeof(int);
    if (ws_size < sorted_bytes + off_bytes + hist_bytes) {
        embed_pe_direct<<<NTOK, 256, 0, stream>>>(text, W, bias, pe, out);
        return;
    }

    int2* sorted   = (int2*)d_ws;
    int*  tile_off = (int*)((char*)d_ws + sorted_bytes);
    int*  hist     = (int*)((char*)d_ws + sorted_bytes + off_bytes);

    (void)hipMemsetAsync(hist, 0, hist_bytes, stream);
    hist_k   <<<NTOK / 256, 256, 0, stream>>>(text, hist);
    scan_k   <<<1, 512, 0, stream>>>(hist, tile_off);
    scatter_k<<<NTOK / 256, 256, 0, stream>>>(text, hist, sorted);
    gather_k <<<NBLK, 256, 0, stream>>>(sorted, tile_off, W, bias, pe, out);
}

// Round 11
// 52.605 us; speedup vs baseline: 1.0592x; 1.0592x over previous
//
#include <hip/hip_runtime.h>

// out[b,s,:] = W[:, text[b,s]] + bias + pe[s,:]
// text: int32 [B,S]; W: f32 [D, VOCAB]; bias: f32 [D]; pe: f32 [MAX_LEN, D]
//
// Round 11: r7 gather EXACTLY (plain loads/stores — round-10's nontemporal
// hints bypassed the 256MB L3 that keeps W resident across runs: 40->56us).
// Single isolated change vs r7: parallel 3-kernel binning (hist/scan/scatter)
// instead of the serial 1-block bin_k, to shrink the serial prefix.

#define VOCAB  32000
#define DMODEL 1024
#define S_LEN  2048
#define B_N    4
#define NTOK   (B_N * S_LEN)     // 8192
#define VT     64                // vocab entries per tile
#define DT     64                // d rows per tile
#define NBIN   (VOCAB / VT)      // 500
#define NDT    (DMODEL / DT)     // 16
#define NBLK   (NBIN * NDT)      // 8000
#define LSTRIDE (VT + 1)         // 65: column reads 2-way only (free)

// ---- pass 1a: parallel histogram (global atomics over 500 bins) ----
__global__ __launch_bounds__(256) void hist_k(const int* __restrict__ text,
                                              int* __restrict__ hist) {
    const int i = blockIdx.x * 256 + threadIdx.x;
    if (i < NTOK) atomicAdd(&hist[text[i] >> 6], 1);
}

// ---- pass 1b: scan 500 bins; tile_off = exclusive starts; hist <- cursor ----
__global__ __launch_bounds__(512) void scan_k(int* __restrict__ hist,
                                              int* __restrict__ tile_off) {
    __shared__ int scn[512];
    const int t = threadIdx.x;
    const int cnt = (t < NBIN) ? hist[t] : 0;
    scn[t] = cnt;
    __syncthreads();
    for (int off = 1; off < 512; off <<= 1) {
        int x = (t >= off) ? scn[t - off] : 0;
        __syncthreads();
        scn[t] += x;
        __syncthreads();
    }
    if (t < NBIN) {
        const int start = scn[t] - cnt;      // exclusive
        tile_off[t] = start;
        hist[t] = start;                     // becomes scatter cursor
    }
    if (t == 0) tile_off[NBIN] = NTOK;
}

// ---- pass 1c: parallel scatter (order within bin irrelevant) ----
__global__ __launch_bounds__(256) void scatter_k(const int* __restrict__ text,
                                                 int* __restrict__ cursor,
                                                 int2* __restrict__ sorted) {
    const int i = blockIdx.x * 256 + threadIdx.x;
    if (i < NTOK) {
        const int tok = text[i];
        const int slot = atomicAdd(&cursor[tok >> 6], 1);
        sorted[slot] = make_int2(tok, i);
    }
}

// ---- pass 2: coalesced W sweep, LDS-staged scatter-free gather (r7 exact) ----
__global__ __launch_bounds__(256, 8) void gather_k(const int2* __restrict__ sorted,
                                                   const int* __restrict__ tile_off,
                                                   const float* __restrict__ W,
                                                   const float* __restrict__ bias,
                                                   const float* __restrict__ pe,
                                                   float* __restrict__ out) {
    __shared__ float lds[DT * LSTRIDE];      // 16.6 KB -> 8 blocks/CU

    const int bid = blockIdx.x;
    const int vt = bid >> 4;                 // 0..499
    const int dt = bid & (NDT - 1);          // 0..15 (bid%8 ~ dt%8 -> XCD affinity)
    const int v0 = vt * VT;
    const int d0 = dt * DT;
    const int t  = threadIdx.x;

    // stage W[d0:d0+64][v0:v0+64] into LDS, coalesced float4 reads
    {
        const int c4 = t & 15;               // float4 column 0..15
        const int r0 = t >> 4;               // row 0..15
        #pragma unroll
        for (int i = 0; i < 4; ++i) {
            const int row = r0 + i * 16;
            const float4 w4 = *reinterpret_cast<const float4*>(
                W + (size_t)(d0 + row) * VOCAB + v0 + c4 * 4);
            float* lp = lds + row * LSTRIDE + c4 * 4;
            lp[0] = w4.x; lp[1] = w4.y; lp[2] = w4.z; lp[3] = w4.w;
        }
    }
    __syncthreads();

    const int a0 = tile_off[vt];
    const int a1 = tile_off[vt + 1];
    const int lane = t & 63;
    const int wv   = t >> 6;                 // 4 tokens in parallel
    const float bv = bias[d0 + lane];

    for (int i = a0 + wv; i < a1; i += 4) {
        const int2 p = sorted[i];            // wave-uniform broadcast
        const int tokl = p.x - v0;
        const int bs   = p.y;
        const int s    = bs & (S_LEN - 1);
        const float wval = lds[lane * LSTRIDE + tokl];   // (lane+tokl)%32: 2-way
        const float pv = pe[(size_t)s * DMODEL + d0 + lane];
        out[(size_t)bs * DMODEL + d0 + lane] = wval + bv + pv;
    }
}

// ---- fallback (ws too small): direct gather ----
__global__ __launch_bounds__(256) void embed_pe_direct(const int* __restrict__ text,
                                                       const float* __restrict__ W,
                                                       const float* __restrict__ bias,
                                                       const float* __restrict__ pe,
                                                       float* __restrict__ out) {
    const int bs = blockIdx.x;
    const int s  = bs & (S_LEN - 1);
    const int tok = text[bs];
    const int d = threadIdx.x << 2;
    const float4 b4 = *reinterpret_cast<const float4*>(bias + d);
    const float4 p4 = *reinterpret_cast<const float4*>(pe + (size_t)s * DMODEL + d);
    const float* wcol = W + (size_t)d * VOCAB + tok;
    float4 o;
    o.x = wcol[0]                 + b4.x + p4.x;
    o.y = wcol[(size_t)VOCAB]     + b4.y + p4.y;
    o.z = wcol[(size_t)2 * VOCAB] + b4.z + p4.z;
    o.w = wcol[(size_t)3 * VOCAB] + b4.w + p4.w;
    *reinterpret_cast<float4*>(out + (size_t)bs * DMODEL + d) = o;
}

extern "C" void kernel_launch(void* const* d_in, const int* in_sizes, int n_in,
                              void* d_out, int out_size, void* d_ws, size_t ws_size,
                              hipStream_t stream) {
    const int*   text = (const int*)d_in[0];
    const float* W    = (const float*)d_in[1];
    const float* bias = (const float*)d_in[2];
    const float* pe   = (const float*)d_in[3];
    float*       out  = (float*)d_out;

    const size_t sorted_bytes = (size_t)NTOK * sizeof(int2);   // 64 KB
    const size_t off_bytes    = (NBIN + 1) * sizeof(int);
    const size_t hist_bytes   = NBIN * sizeof(int);
    if (ws_size < sorted_bytes + off_bytes + hist_bytes) {
        embed_pe_direct<<<NTOK, 256, 0, stream>>>(text, W, bias, pe, out);
        return;
    }

    int2* sorted   = (int2*)d_ws;
    int*  tile_off = (int*)((char*)d_ws + sorted_bytes);
    int*  hist     = (int*)((char*)d_ws + sorted_bytes + off_bytes);

    (void)hipMemsetAsync(hist, 0, hist_bytes, stream);
    hist_k   <<<NTOK / 256, 256, 0, stream>>>(text, hist);
    scan_k   <<<1, 512, 0, stream>>>(hist, tile_off);
    scatter_k<<<NTOK / 256, 256, 0, stream>>>(text, hist, sorted);
    gather_k <<<NBLK, 256, 0, stream>>>(sorted, tile_off, W, bias, pe, out);
}

// Round 12
// 39.105 us; speedup vs baseline: 1.4248x; 1.3452x over previous
//
#include <hip/hip_runtime.h>

// out[b,s,:] = W[:, text[b,s]] + bias + pe[s,:]
// text: int32 [B,S]; W: f32 [D, VOCAB]; bias: f32 [D]; pe: f32 [MAX_LEN, D]
//
// Round 12 = r7 (best, 40.2us: fused 1-block bin + 8000-block W-sweep gather)
// + two micro-fixes:
//  (1) bin_k scan: single-wave shfl scan (no barrier storm) instead of
//      512-wide Hillis-Steele (~18 syncthreads on 16 waves);
//  (2) gather process phase vectorized: transposed LDS [v][d] with 272B rows
//      -> ds_read_b128, float4 pe loads + out stores (4x fewer instructions,
//      same bytes). LDS 17.4KB keeps 8 blocks/CU.
// r10 lesson: NO nontemporal hints (W/out must stay L3-cacheable).
// r11 lesson: NO multi-dispatch binning (launch gaps cost ~12us).

#define VOCAB  32000
#define DMODEL 1024
#define S_LEN  2048
#define B_N    4
#define NTOK   (B_N * S_LEN)     // 8192
#define VT     64                // vocab entries per tile
#define DT     64                // d rows per tile
#define NBIN   (VOCAB / VT)      // 500
#define NDT    (DMODEL / DT)     // 16
#define NBLK   (NBIN * NDT)      // 8000
#define LROW   (DT + 4)          // 68 floats = 272 B rows (16B-aligned)

// ---- pass 1: fused bin (hist + wave-scan + scatter), single block ----
__global__ __launch_bounds__(1024) void bin_k(const int* __restrict__ text,
                                              int2* __restrict__ sorted,
                                              int* __restrict__ tile_off) {
    __shared__ int cnt[512];
    __shared__ int cur[512];
    const int t = threadIdx.x;
    if (t < 512) cnt[t] = 0;
    __syncthreads();

    int toks[8];
    #pragma unroll
    for (int j = 0; j < 8; ++j) {
        toks[j] = text[t * 8 + j];
        atomicAdd(&cnt[toks[j] >> 6], 1);
    }
    __syncthreads();

    // exclusive scan over 512 bins by wave 0: 8 bins/lane + shfl wave-scan
    if (t < 64) {
        const int base = t * 8;
        int loc[8];
        int s = 0;
        #pragma unroll
        for (int j = 0; j < 8; ++j) { loc[j] = s; s += cnt[base + j]; }
        const int own = s;
        #pragma unroll
        for (int off = 1; off < 64; off <<= 1) {
            const int n = __shfl_up(s, off, 64);
            if (t >= off) s += n;
        }
        const int excl = s - own;            // exclusive prefix of this lane
        #pragma unroll
        for (int j = 0; j < 8; ++j) {
            const int v = excl + loc[j];
            cur[base + j] = v;
            if (base + j <= NBIN) tile_off[base + j] = v;  // 0..500 (bins 500+ empty)
        }
    }
    __syncthreads();

    #pragma unroll
    for (int j = 0; j < 8; ++j) {
        const int tok = toks[j];
        const int slot = atomicAdd(&cur[tok >> 6], 1);
        sorted[slot] = make_int2(tok, t * 8 + j);
    }
}

// ---- pass 2: coalesced W sweep, transposed-LDS gather, float4 epilogue ----
__global__ __launch_bounds__(256, 8) void gather_k(const int2* __restrict__ sorted,
                                                   const int* __restrict__ tile_off,
                                                   const float* __restrict__ W,
                                                   const float* __restrict__ bias,
                                                   const float* __restrict__ pe,
                                                   float* __restrict__ out) {
    __shared__ float lds[VT][LROW];          // 64 x 68 x 4B = 17.4 KB -> 8 blk/CU

    const int bid = blockIdx.x;
    const int vt = bid >> 4;                 // 0..499
    const int dt = bid & (NDT - 1);          // 0..15
    const int v0 = vt * VT;
    const int d0 = dt * DT;
    const int t  = threadIdx.x;

    // stage W[d0:d0+64][v0:v0+64] -> transposed lds[v][d], coalesced f4 reads
    {
        const int c4 = t & 15;               // float4 column (v) 0..15
        const int r0 = t >> 4;               // row (d) 0..15
        #pragma unroll
        for (int i = 0; i < 4; ++i) {
            const int row = r0 + i * 16;
            const float4 w4 = *reinterpret_cast<const float4*>(
                W + (size_t)(d0 + row) * VOCAB + v0 + c4 * 4);
            lds[c4 * 4 + 0][row] = w4.x;
            lds[c4 * 4 + 1][row] = w4.y;
            lds[c4 * 4 + 2][row] = w4.z;
            lds[c4 * 4 + 3][row] = w4.w;
        }
    }
    __syncthreads();

    const int a0 = tile_off[vt];
    const int a1 = tile_off[vt + 1];
    const int lane = t & 63;
    const int wv   = t >> 6;                 // wave 0..3
    const int grp  = lane >> 4;              // token group 0..3 within wave
    const int ld   = lane & 15;              // d-float4 index 0..15
    const int d    = d0 + ld * 4;
    const float4 b4 = *reinterpret_cast<const float4*>(bias + d);

    // 16 tokens in flight per wave-quad; per token: 1 b128 LDS read,
    // 1 dwordx4 pe load, 1 dwordx4 out store (256B contiguous per 16 lanes)
    for (int i = a0 + wv * 4 + grp; i < a1; i += 16) {
        const int2 p = sorted[i];
        const int tokl = p.x - v0;
        const int bs   = p.y;
        const int s    = bs & (S_LEN - 1);
        const float4 w4 = *reinterpret_cast<const float4*>(&lds[tokl][ld * 4]);
        const float4 p4 = *reinterpret_cast<const float4*>(pe + (size_t)s * DMODEL + d);
        float4 o;
        o.x = w4.x + b4.x + p4.x;
        o.y = w4.y + b4.y + p4.y;
        o.z = w4.z + b4.z + p4.z;
        o.w = w4.w + b4.w + p4.w;
        *reinterpret_cast<float4*>(out + (size_t)bs * DMODEL + d) = o;
    }
}

// ---- fallback (ws too small): direct gather ----
__global__ __launch_bounds__(256) void embed_pe_direct(const int* __restrict__ text,
                                                       const float* __restrict__ W,
                                                       const float* __restrict__ bias,
                                                       const float* __restrict__ pe,
                                                       float* __restrict__ out) {
    const int bs = blockIdx.x;
    const int s  = bs & (S_LEN - 1);
    const int tok = text[bs];
    const int d = threadIdx.x << 2;
    const float4 b4 = *reinterpret_cast<const float4*>(bias + d);
    const float4 p4 = *reinterpret_cast<const float4*>(pe + (size_t)s * DMODEL + d);
    const float* wcol = W + (size_t)d * VOCAB + tok;
    float4 o;
    o.x = wcol[0]                 + b4.x + p4.x;
    o.y = wcol[(size_t)VOCAB]     + b4.y + p4.y;
    o.z = wcol[(size_t)2 * VOCAB] + b4.z + p4.z;
    o.w = wcol[(size_t)3 * VOCAB] + b4.w + p4.w;
    *reinterpret_cast<float4*>(out + (size_t)bs * DMODEL + d) = o;
}

extern "C" void kernel_launch(void* const* d_in, const int* in_sizes, int n_in,
                              void* d_out, int out_size, void* d_ws, size_t ws_size,
                              hipStream_t stream) {
    const int*   text = (const int*)d_in[0];
    const float* W    = (const float*)d_in[1];
    const float* bias = (const float*)d_in[2];
    const float* pe   = (const float*)d_in[3];
    float*       out  = (float*)d_out;

    const size_t sorted_bytes = (size_t)NTOK * sizeof(int2);   // 64 KB
    const size_t off_bytes    = (NBIN + 1) * sizeof(int);
    if (ws_size < sorted_bytes + off_bytes) {
        embed_pe_direct<<<NTOK, 256, 0, stream>>>(text, W, bias, pe, out);
        return;
    }

    int2* sorted   = (int2*)d_ws;
    int*  tile_off = (int*)((char*)d_ws + sorted_bytes);

    bin_k   <<<1, 1024, 0, stream>>>(text, sorted, tile_off);
    gather_k<<<NBLK, 256, 0, stream>>>(sorted, tile_off, W, bias, pe, out);
}